// Round 10
// baseline (755.177 us; speedup 1.0000x reference)
//
#include <hip/hip_runtime.h>
#include <hip/hip_bf16.h>

#define D 64
#define THREADS 256
#define BKT_BITS 9                 // 512 nodes per bucket
#define BKT_NODES (1 << BKT_BITS)
#define CHUNK 8192                 // edges per phase-0 block

// ---- bf16 helpers (bit tricks, RNE) ----
__device__ __forceinline__ unsigned f2bf(float f) {
    unsigned u = __float_as_uint(f);
    return (u + 0x7fffu + ((u >> 16) & 1u)) >> 16;
}
__device__ __forceinline__ float2 bfpair(unsigned v) {
    return make_float2(__uint_as_float(v << 16), __uint_as_float(v & 0xffff0000u));
}

// ---- software grid barrier (all blocks guaranteed co-resident: 392 blocks,
//      256 thr, 5.2KB LDS, ~32 VGPR -> 8 blocks/CU * 256 CUs = 2048 slots) ----
__device__ __forceinline__ void gsync(int* cnt, int* gen, int nblk) {
    __syncthreads();
    if (threadIdx.x == 0) {
        int g = __hip_atomic_load(gen, __ATOMIC_RELAXED, __HIP_MEMORY_SCOPE_AGENT);
        __threadfence();
        int a = __hip_atomic_fetch_add(cnt, 1, __ATOMIC_ACQ_REL, __HIP_MEMORY_SCOPE_AGENT);
        if (a == nblk - 1) {
            __hip_atomic_store(cnt, 0, __ATOMIC_RELAXED, __HIP_MEMORY_SCOPE_AGENT);
            __hip_atomic_fetch_add(gen, 1, __ATOMIC_ACQ_REL, __HIP_MEMORY_SCOPE_AGENT);
        } else {
            while (__hip_atomic_load(gen, __ATOMIC_ACQUIRE, __HIP_MEMORY_SCOPE_AGENT) == g)
                __builtin_amdgcn_s_sleep(1);
        }
        __threadfence();
    }
    __syncthreads();
}

// ---- fused build: hist -> scans -> bucket scatter -> norm -> placement,
//      with tobf16 running concurrently on the second half of the grid ----
__global__ __launch_bounds__(256)
void build_kernel(const float* __restrict__ h, const float* __restrict__ w,
                  const int* __restrict__ src, const int* __restrict__ dst,
                  int* __restrict__ blockCnt, int* __restrict__ total,
                  int* __restrict__ bstart, int2* __restrict__ temp,
                  int2* __restrict__ packed, int* __restrict__ rowptr,
                  float* __restrict__ norm, unsigned* __restrict__ h0bf,
                  int* __restrict__ bar,
                  int N, int E, int B, int NBLK, long long nd4) {
    __shared__ int   lds_i[BKT_NODES];
    __shared__ float lds_f[BKT_NODES];
    __shared__ int   sm[256];
    int* cnt = bar;      // barrier count
    int* gen = bar + 1;  // barrier generation
    const int blk = blockIdx.x, t = threadIdx.x;
    const int TOTB = NBLK + 196;

    // ---- phase 0: blk<NBLK: coarse-bucket histogram; else: h -> bf16 ----
    if (blk < NBLK) {
        lds_i[t] = 0;
        __syncthreads();
        int base = blk * CHUNK, end = min(base + CHUNK, E);
        for (int e = base + t; e < end; e += THREADS)
            atomicAdd(&lds_i[dst[e] >> BKT_BITS], 1);
        __syncthreads();
        if (t < B) blockCnt[(long long)blk * B + t] = lds_i[t];
    } else {
        long long i0 = (long long)(blk - NBLK) * THREADS + t;
        for (long long i = i0; i < nd4; i += (long long)196 * THREADS) {
            float4 v = ((const float4*)h)[i];
            ((uint2*)h0bf)[i] = make_uint2(f2bf(v.x) | (f2bf(v.y) << 16),
                                           f2bf(v.z) | (f2bf(v.w) << 16));
        }
    }
    gsync(cnt, gen, TOTB);

    // ---- phase 1: blk<B: per-bucket exclusive scan over blocks ----
    if (blk < B) {
        int run = 0;
        for (int base = 0; base < NBLK; base += 256) {
            int i = base + t;
            int v = (i < NBLK) ? blockCnt[(long long)i * B + blk] : 0;
            sm[t] = v;
            __syncthreads();
            for (int off = 1; off < 256; off <<= 1) {
                int u = (t >= off) ? sm[t - off] : 0;
                __syncthreads();
                sm[t] += u;
                __syncthreads();
            }
            if (i < NBLK) blockCnt[(long long)i * B + blk] = run + sm[t] - v;
            run += sm[255];
            __syncthreads();
        }
        if (t == 0) total[blk] = run;
    }
    gsync(cnt, gen, TOTB);

    // ---- phase 2: blk==0: exclusive scan of bucket totals ----
    if (blk == 0) {
        int run = 0;
        for (int base = 0; base < B; base += 256) {
            int i = base + t;
            int v = (i < B) ? total[i] : 0;
            sm[t] = v;
            __syncthreads();
            for (int off = 1; off < 256; off <<= 1) {
                int u = (t >= off) ? sm[t - off] : 0;
                __syncthreads();
                sm[t] += u;
                __syncthreads();
            }
            if (i < B) bstart[i] = run + sm[t] - v;
            run += sm[255];
            __syncthreads();
        }
        if (t == 0) bstart[B] = E;
    }
    gsync(cnt, gen, TOTB);

    // ---- phase 3: blk<NBLK: scatter edges into bucket-partitioned temp ----
    if (blk < NBLK) {
        if (t < B) lds_i[t] = bstart[t] + blockCnt[(long long)blk * B + t];
        __syncthreads();
        int base = blk * CHUNK, end = min(base + CHUNK, E);
        for (int e = base + t; e < end; e += THREADS) {
            int d = dst[e];
            int b = d >> BKT_BITS;
            int pos = atomicAdd(&lds_i[b], 1);                 // LDS atomic w/ return
            temp[pos] = make_int2(src[e] | ((d & (BKT_NODES - 1)) << 17),
                                  __float_as_int(w[e]));
        }
    }
    gsync(cnt, gen, TOTB);

    // ---- phase 4: blk<B: per-node hist + weighted degree -> rowptr + norm;
    //      keep cursors (ebeg+offset) in LDS for phase 5 ----
    int ebeg = 0, eend = 0;
    if (blk < B) {
        ebeg = bstart[blk]; eend = bstart[blk + 1];
        for (int i = t; i < BKT_NODES; i += THREADS) { lds_i[i] = 0; lds_f[i] = 0.0f; }
        __syncthreads();
        for (int e = ebeg + t; e < eend; e += THREADS) {
            int2 pk = temp[e];
            int dl = (pk.x >> 17) & (BKT_NODES - 1);
            atomicAdd(&lds_i[dl], 1);
            atomicAdd(&lds_f[dl], __int_as_float(pk.y));
        }
        __syncthreads();
        int run = 0;
        for (int base = 0; base < BKT_NODES; base += 256) {
            int v = lds_i[base + t];
            sm[t] = v;
            __syncthreads();
            for (int off = 1; off < 256; off <<= 1) {
                int u = (t >= off) ? sm[t - off] : 0;
                __syncthreads();
                sm[t] += u;
                __syncthreads();
            }
            lds_i[base + t] = ebeg + run + sm[t] - v;          // cursor for phase 5
            run += sm[255];
            __syncthreads();
        }
        int node0 = blk << BKT_BITS;
        for (int i = t; i < BKT_NODES; i += THREADS) {
            int node = node0 + i;
            if (node < N) {
                rowptr[node] = lds_i[i];
                norm[node] = rsqrtf(fmaxf(lds_f[i], 1.0f));
            }
        }
        if (blk == 0 && t == 0) rowptr[N] = E;
    }
    gsync(cnt, gen, TOTB);

    // ---- phase 5: blk<B: placement with coef = w * norm[src] baked in ----
    if (blk < B) {
        for (int e = ebeg + t; e < eend; e += THREADS) {
            int2 pk = temp[e];
            int dl = (pk.x >> 17) & (BKT_NODES - 1);
            int s = pk.x & 0x1ffff;
            int pos = atomicAdd(&lds_i[dl], 1);                // LDS atomic w/ return
            float c = __int_as_float(pk.y) * norm[s];
            packed[pos] = make_int2(s, __float_as_int(c));
        }
    }
}

// ---- gather layer 1: quarter-wave (16 lanes) per node, lane = 4 dims, unroll 4 ----
// r6/r9-proven register shape (4 int2 meta + 4 uint2 rows + 16 accs = 32 VGPRs)
__global__ void gather1_kernel(const uint2* __restrict__ h_in, const int2* __restrict__ packed,
                               const int* __restrict__ rowptr, const float* __restrict__ norm,
                               uint2* __restrict__ h_out, int N) {
    int node = blockIdx.x * (blockDim.x >> 4) + (threadIdx.x >> 4);
    int lane = threadIdx.x & 15;
    if (node >= N) return;
    int j = rowptr[node], end = rowptr[node + 1];
    float a00 = 0, a01 = 0, a02 = 0, a03 = 0;
    float a10 = 0, a11 = 0, a12 = 0, a13 = 0;
    float a20 = 0, a21 = 0, a22 = 0, a23 = 0;
    float a30 = 0, a31 = 0, a32 = 0, a33 = 0;
    for (; j + 4 <= end; j += 4) {
        int2 p0 = packed[j], p1 = packed[j + 1], p2 = packed[j + 2], p3 = packed[j + 3];
        uint2 r0 = h_in[((long long)p0.x << 4) + lane];
        uint2 r1 = h_in[((long long)p1.x << 4) + lane];
        uint2 r2 = h_in[((long long)p2.x << 4) + lane];
        uint2 r3 = h_in[((long long)p3.x << 4) + lane];
        float c0 = __int_as_float(p0.y);
        float c1 = __int_as_float(p1.y);
        float c2 = __int_as_float(p2.y);
        float c3 = __int_as_float(p3.y);
        float2 f0a = bfpair(r0.x), f0b = bfpair(r0.y);
        float2 f1a = bfpair(r1.x), f1b = bfpair(r1.y);
        float2 f2a = bfpair(r2.x), f2b = bfpair(r2.y);
        float2 f3a = bfpair(r3.x), f3b = bfpair(r3.y);
        a00 = fmaf(f0a.x, c0, a00); a01 = fmaf(f0a.y, c0, a01);
        a02 = fmaf(f0b.x, c0, a02); a03 = fmaf(f0b.y, c0, a03);
        a10 = fmaf(f1a.x, c1, a10); a11 = fmaf(f1a.y, c1, a11);
        a12 = fmaf(f1b.x, c1, a12); a13 = fmaf(f1b.y, c1, a13);
        a20 = fmaf(f2a.x, c2, a20); a21 = fmaf(f2a.y, c2, a21);
        a22 = fmaf(f2b.x, c2, a22); a23 = fmaf(f2b.y, c2, a23);
        a30 = fmaf(f3a.x, c3, a30); a31 = fmaf(f3a.y, c3, a31);
        a32 = fmaf(f3b.x, c3, a32); a33 = fmaf(f3b.y, c3, a33);
    }
    for (; j < end; ++j) {
        int2 p = packed[j];
        uint2 r = h_in[((long long)p.x << 4) + lane];
        float c = __int_as_float(p.y);
        float2 fa = bfpair(r.x), fb = bfpair(r.y);
        a00 = fmaf(fa.x, c, a00); a01 = fmaf(fa.y, c, a01);
        a02 = fmaf(fb.x, c, a02); a03 = fmaf(fb.y, c, a03);
    }
    float nv = norm[node];
    float d0 = ((a00 + a10) + (a20 + a30)) * nv;
    float d1 = ((a01 + a11) + (a21 + a31)) * nv;
    float d2 = ((a02 + a12) + (a22 + a32)) * nv;
    float d3 = ((a03 + a13) + (a23 + a33)) * nv;
    h_out[((long long)node << 4) + lane] =
        make_uint2(f2bf(d0) | (f2bf(d1) << 16), f2bf(d2) | (f2bf(d3) << 16));
}

// ---- gather layer 2 + mean: out = (h0 + h1 + norm*sum h1[src]*coef)/3 ----
__global__ void gather2_final_kernel(const uint2* __restrict__ h0bf, const uint2* __restrict__ h1bf,
                                     const int2* __restrict__ packed, const int* __restrict__ rowptr,
                                     const float* __restrict__ norm, float* __restrict__ out, int N) {
    int node = blockIdx.x * (blockDim.x >> 4) + (threadIdx.x >> 4);
    int lane = threadIdx.x & 15;
    if (node >= N) return;
    int j = rowptr[node], end = rowptr[node + 1];
    float a00 = 0, a01 = 0, a02 = 0, a03 = 0;
    float a10 = 0, a11 = 0, a12 = 0, a13 = 0;
    float a20 = 0, a21 = 0, a22 = 0, a23 = 0;
    float a30 = 0, a31 = 0, a32 = 0, a33 = 0;
    for (; j + 4 <= end; j += 4) {
        int2 p0 = packed[j], p1 = packed[j + 1], p2 = packed[j + 2], p3 = packed[j + 3];
        uint2 r0 = h1bf[((long long)p0.x << 4) + lane];
        uint2 r1 = h1bf[((long long)p1.x << 4) + lane];
        uint2 r2 = h1bf[((long long)p2.x << 4) + lane];
        uint2 r3 = h1bf[((long long)p3.x << 4) + lane];
        float c0 = __int_as_float(p0.y);
        float c1 = __int_as_float(p1.y);
        float c2 = __int_as_float(p2.y);
        float c3 = __int_as_float(p3.y);
        float2 f0a = bfpair(r0.x), f0b = bfpair(r0.y);
        float2 f1a = bfpair(r1.x), f1b = bfpair(r1.y);
        float2 f2a = bfpair(r2.x), f2b = bfpair(r2.y);
        float2 f3a = bfpair(r3.x), f3b = bfpair(r3.y);
        a00 = fmaf(f0a.x, c0, a00); a01 = fmaf(f0a.y, c0, a01);
        a02 = fmaf(f0b.x, c0, a02); a03 = fmaf(f0b.y, c0, a03);
        a10 = fmaf(f1a.x, c1, a10); a11 = fmaf(f1a.y, c1, a11);
        a12 = fmaf(f1b.x, c1, a12); a13 = fmaf(f1b.y, c1, a13);
        a20 = fmaf(f2a.x, c2, a20); a21 = fmaf(f2a.y, c2, a21);
        a22 = fmaf(f2b.x, c2, a22); a23 = fmaf(f2b.y, c2, a23);
        a30 = fmaf(f3a.x, c3, a30); a31 = fmaf(f3a.y, c3, a31);
        a32 = fmaf(f3b.x, c3, a32); a33 = fmaf(f3b.y, c3, a33);
    }
    for (; j < end; ++j) {
        int2 p = packed[j];
        uint2 r = h1bf[((long long)p.x << 4) + lane];
        float c = __int_as_float(p.y);
        float2 fa = bfpair(r.x), fb = bfpair(r.y);
        a00 = fmaf(fa.x, c, a00); a01 = fmaf(fa.y, c, a01);
        a02 = fmaf(fb.x, c, a02); a03 = fmaf(fb.y, c, a03);
    }
    long long idx = ((long long)node << 4) + lane;
    float nv = norm[node];
    uint2 h0r = h0bf[idx], h1r = h1bf[idx];
    float2 h0a = bfpair(h0r.x), h0b = bfpair(h0r.y);
    float2 h1a = bfpair(h1r.x), h1b = bfpair(h1r.y);
    float4 o;
    o.x = (h0a.x + h1a.x + ((a00 + a10) + (a20 + a30)) * nv) * (1.0f / 3.0f);
    o.y = (h0a.y + h1a.y + ((a01 + a11) + (a21 + a31)) * nv) * (1.0f / 3.0f);
    o.z = (h0b.x + h1b.x + ((a02 + a12) + (a22 + a32)) * nv) * (1.0f / 3.0f);
    o.w = (h0b.y + h1b.y + ((a03 + a13) + (a23 + a33)) * nv) * (1.0f / 3.0f);
    ((float4*)out)[idx] = o;
}

extern "C" void kernel_launch(void* const* d_in, const int* in_sizes, int n_in,
                              void* d_out, int out_size, void* d_ws, size_t ws_size,
                              hipStream_t stream) {
    const float* h   = (const float*)d_in[0];
    const float* w   = (const float*)d_in[1];
    const int*   src = (const int*)d_in[2];
    const int*   dst = (const int*)d_in[3];
    const int N = in_sizes[0] / D;   // 100000
    const int E = in_sizes[1];       // 1600000
    float* out = (float*)d_out;

    const int B = (N + BKT_NODES - 1) >> BKT_BITS;   // 196
    const int NBLK = (E + CHUNK - 1) / CHUNK;        // 196
    const int TOTB = NBLK + 196;                     // 392 blocks (co-resident)

    // ---- workspace layout ----
    char* ws = (char*)d_ws;
    size_t off = 0;
    auto alloc = [&](size_t bytes, size_t align) -> char* {
        off = (off + align - 1) & ~(align - 1);
        char* p = ws + off;
        off += bytes;
        return p;
    };
    float* norm     = (float*)alloc((size_t)N * 4, 16);
    int*   rowptr   = (int*)  alloc((size_t)(N + 1) * 4, 16);
    int*   total    = (int*)  alloc((size_t)B * 4, 16);
    int*   bstart   = (int*)  alloc((size_t)(B + 1) * 4, 16);
    int*   bar      = (int*)  alloc(2 * 4, 16);
    int*   blockCnt = (int*)  alloc((size_t)NBLK * B * 4, 16);
    int2*  packed   = (int2*) alloc((size_t)E * 8, 16);
    // temp (build phase) time-shares with h1bf (gather phase)
    char*  shared_region = alloc((size_t)E * 8, 128);
    int2*     temp = (int2*)shared_region;
    unsigned* h1bf = (unsigned*)shared_region;
    unsigned* h0bf = (unsigned*)alloc((size_t)N * D * 2, 128);

    const int nodes_per_block = THREADS / 16;        // quarter-wave per node
    const int gather_blocks = (N + nodes_per_block - 1) / nodes_per_block;
    const long long nd4 = (long long)N * D / 4;

    // zero the barrier (ws is poisoned to 0xAA before every call)
    hipMemsetAsync(bar, 0, 8, stream);

    // fused build (6 phases + concurrent tobf16), single dispatch
    build_kernel<<<TOTB, THREADS, 0, stream>>>(h, w, src, dst, blockCnt, total, bstart,
                                               temp, packed, rowptr, norm, h0bf, bar,
                                               N, E, B, NBLK, nd4);

    // gathers (r9-proven register shape: 4-deep MLP, 32 VGPRs)
    gather1_kernel<<<gather_blocks, THREADS, 0, stream>>>((const uint2*)h0bf, packed, rowptr,
                                                          norm, (uint2*)h1bf, N);
    gather2_final_kernel<<<gather_blocks, THREADS, 0, stream>>>((const uint2*)h0bf, (const uint2*)h1bf,
                                                                packed, rowptr, norm, out, N);
}